// Round 6
// baseline (7271.184 us; speedup 1.0000x reference)
//
#include <hip/hip_runtime.h>
#include <math.h>

#define N_NODES 200000
#define H_CH    128
#define GRP     64          // channel group width (2 groups of 64)
#define NNZ_E   3200000
#define K_DEG   15

// bucketed CSR build parameters
#define EPB     4096        // edges per block in bucket pass A
#define BSHIFT  9           // 512 rows per bucket
#define BROWS   512
#define NBUCK   391         // ceil(200000 / 512)
#define BCAP    9216        // per-bucket staging capacity (mean 8192, +11 sigma)

// column chunking: chunk = col >> 15  ->  7 chunks (slice = 8.4 MB of compact T)
#define NCH     7

// chunked cheb kernel geometry: ALL blocks co-resident (soft-synchronized
// chunk sweep). 1000 blocks x 8 waves x 25 rows = 200000 exactly.
#define CBLK    1000
#define RPWV    25

// ---------- softmax over 16 logits ----------
__global__ void softmax_k(const float* __restrict__ logits, float* __restrict__ w) {
    if (threadIdx.x == 0) {
        float m = -1e30f;
        for (int i = 0; i <= K_DEG; ++i) m = fmaxf(m, logits[i]);
        float e[K_DEG + 1];
        float s = 0.f;
        for (int i = 0; i <= K_DEG; ++i) { e[i] = expf(logits[i] - m); s += e[i]; }
        float inv = 1.0f / s;
        for (int i = 0; i <= K_DEG; ++i) w[i] = e[i] * inv;
    }
}

// ---------- bucket pass A: block-local LDS binning by row bucket ----------
__global__ __launch_bounds__(256) void bucketA_k(
    const int* __restrict__ row, const int* __restrict__ col,
    const float* __restrict__ vals,
    int* __restrict__ gfill, uint2* __restrict__ stag, int nnz) {
    __shared__ int cnt[NBUCK];
    __shared__ int excl[NBUCK];
    __shared__ int gbase[NBUCK];
    __shared__ int sm[256];
    __shared__ uint2 sstag[EPB];
    __shared__ unsigned short sb[EPB];

    int tid = threadIdx.x;
    int base = blockIdx.x * EPB;

    for (int t = tid; t < NBUCK; t += 256) cnt[t] = 0;
    __syncthreads();

    int r[16], c[16], b[16];
    float v[16];
#pragma unroll
    for (int j = 0; j < 16; ++j) {
        int i = base + j * 256 + tid;
        if (i < nnz) {
            r[j] = row[i]; c[j] = col[i]; v[j] = vals[i];
            b[j] = r[j] >> BSHIFT;
            atomicAdd(&cnt[b[j]], 1);
        } else {
            b[j] = -1;
        }
    }
    __syncthreads();

    {
        int b0 = 2 * tid, b1 = 2 * tid + 1;
        int c0 = (b0 < NBUCK) ? cnt[b0] : 0;
        int c1 = (b1 < NBUCK) ? cnt[b1] : 0;
        int pair = c0 + c1;
        sm[tid] = pair;
        __syncthreads();
        int incl = pair;
        for (int off = 1; off < 256; off <<= 1) {
            int tv = (tid >= off) ? sm[tid - off] : 0;
            __syncthreads();
            incl += tv;
            sm[tid] = incl;
            __syncthreads();
        }
        int pexcl = incl - pair;
        if (b0 < NBUCK) excl[b0] = pexcl;
        if (b1 < NBUCK) excl[b1] = pexcl + c0;
    }
    __syncthreads();

    for (int t = tid; t < NBUCK; t += 256) {
        int cb = cnt[t];
        gbase[t] = (cb > 0) ? atomicAdd(&gfill[t], cb) : 0;
    }
    __syncthreads();
    for (int t = tid; t < NBUCK; t += 256) cnt[t] = excl[t];
    __syncthreads();

#pragma unroll
    for (int j = 0; j < 16; ++j) {
        if (b[j] >= 0) {
            int p = atomicAdd(&cnt[b[j]], 1);
            sstag[p] = make_uint2(((unsigned)(r[j] & 511) << 18) | (unsigned)c[j],
                                  __float_as_uint(v[j]));
            sb[p] = (unsigned short)b[j];
        }
    }
    __syncthreads();

    int tot = nnz - base; if (tot > EPB) tot = EPB;
    for (int i = tid; i < tot; i += 256) {
        int bb = sb[i];
        size_t gp = (size_t)bb * BCAP + gbase[bb] + (i - excl[bb]);
        stag[gp] = sstag[i];
    }
}

// ---------- tiny scan over 391 bucket totals ----------
__global__ void scanG_k(const int* __restrict__ gfill, int* __restrict__ bbase,
                        int* __restrict__ row_ptr) {
    __shared__ int sm[256];
    int tid = threadIdx.x;
    int j0 = 2 * tid, j1 = 2 * tid + 1;
    int c0 = (j0 < NBUCK) ? gfill[j0] : 0;
    int c1 = (j1 < NBUCK) ? gfill[j1] : 0;
    int pair = c0 + c1;
    sm[tid] = pair;
    __syncthreads();
    int incl = pair;
    for (int off = 1; off < 256; off <<= 1) {
        int t = (tid >= off) ? sm[tid - off] : 0;
        __syncthreads();
        incl += t;
        sm[tid] = incl;
        __syncthreads();
    }
    int pexcl = incl - pair;
    if (j0 < NBUCK) bbase[j0] = pexcl;
    if (j1 < NBUCK) bbase[j1] = pexcl + c0;
    if (tid == 0) row_ptr[N_NODES] = NNZ_E;
}

// ---------- bucket pass B: bucket-local CSR build, chunk-grouped in-row ----------
// LDS histogram over (row, chunk) [512 x 8, chunk slot 7 always zero], exclusive
// scan, then scatter. Emits rcb[r*8 + c] = start of chunk c in row r; slot 7 =
// row end (falls out of the zero-count slot in the exclusive scan).
__global__ __launch_bounds__(256) void bucketB_k(
    const uint2* __restrict__ stag, const int* __restrict__ gfill,
    const int* __restrict__ bbase, int* __restrict__ row_ptr,
    int* __restrict__ rcb, int2* __restrict__ csr) {
    __shared__ int hist[BROWS * 8];
    __shared__ int lexcl[BROWS * 8];
    __shared__ int sm[256];
    int b = blockIdx.x;
    int n = gfill[b];
    int cs = bbase[b];
    const uint2* s = stag + (size_t)b * BCAP;
    int tid = threadIdx.x;

    for (int t = tid; t < BROWS * 8; t += 256) hist[t] = 0;
    __syncthreads();
    for (int i = tid; i < n; i += 256) {
        unsigned key = s[i].x;
        int rl = (int)(key >> 18);
        int c = (int)((key & 0x3FFFF) >> 15);         // 0..6
        atomicAdd(&hist[(rl << 3) | c], 1);
    }
    __syncthreads();

    // exclusive scan over 4096 entries: 16 contiguous per thread + block scan
    int base16 = tid * 16;
    int vloc[16];
    int tsum = 0;
#pragma unroll
    for (int q = 0; q < 16; ++q) { vloc[q] = tsum; tsum += hist[base16 + q]; }
    sm[tid] = tsum;
    __syncthreads();
    int incl = tsum;
    for (int off = 1; off < 256; off <<= 1) {
        int t = (tid >= off) ? sm[tid - off] : 0;
        __syncthreads();
        incl += t;
        sm[tid] = incl;
        __syncthreads();
    }
    int texcl = incl - tsum;
#pragma unroll
    for (int q = 0; q < 16; ++q) lexcl[base16 + q] = texcl + vloc[q];
    __syncthreads();

    // emit row_ptr + rcb
    int rbase = b << BSHIFT;
    for (int rl = tid; rl < BROWS; rl += 256) {
        int r = rbase + rl;
        if (r < N_NODES) {
            row_ptr[r] = cs + lexcl[rl << 3];
#pragma unroll
            for (int c2 = 0; c2 < 8; ++c2)
                rcb[(size_t)r * 8 + c2] = cs + lexcl[(rl << 3) | c2];
        }
    }
    // convert to cursors
    for (int t = tid; t < BROWS * 8; t += 256) hist[t] = lexcl[t];
    __syncthreads();

    for (int i = tid; i < n; i += 256) {
        uint2 e = s[i];
        int rl = (int)(e.x >> 18);
        unsigned col = e.x & 0x3FFFF;
        int c = (int)(col >> 15);
        int p = cs + atomicAdd(&hist[(rl << 3) | c], 1);
        int2 cv;
        cv.x = (int)col;
        cv.y = (int)e.y;
        csr[p] = cv;
    }
}

// ---------- first fused kernel (per 64-ch group), 8-wide edge unroll ----------
__global__ __launch_bounds__(512) void first_k(
    const int* __restrict__ rp, const int2* __restrict__ csr,
    const float* __restrict__ x, float* __restrict__ T1g, float* __restrict__ out,
    const float* __restrict__ w, const float* __restrict__ alpha_p, int goff) {
    int wid = blockIdx.x * 8 + (threadIdx.x >> 6);
    int r = __builtin_amdgcn_readfirstlane(wid);
    if (r >= N_NODES) return;
    int lane = threadIdx.x & 63;
    const float* base = x + goff + lane;
    int e0 = rp[r], e1 = rp[r + 1];
    float a0 = 0.f, a1 = 0.f, a2 = 0.f, a3 = 0.f;
    float a4 = 0.f, a5 = 0.f, a6 = 0.f, a7 = 0.f;
    int e = e0;
    for (; e + 8 <= e1; e += 8) {
        int2 cv0 = csr[e],     cv1 = csr[e + 1], cv2 = csr[e + 2], cv3 = csr[e + 3];
        int2 cv4 = csr[e + 4], cv5 = csr[e + 5], cv6 = csr[e + 6], cv7 = csr[e + 7];
        a0 = fmaf(__int_as_float(cv0.y), base[(unsigned)cv0.x * H_CH], a0);
        a1 = fmaf(__int_as_float(cv1.y), base[(unsigned)cv1.x * H_CH], a1);
        a2 = fmaf(__int_as_float(cv2.y), base[(unsigned)cv2.x * H_CH], a2);
        a3 = fmaf(__int_as_float(cv3.y), base[(unsigned)cv3.x * H_CH], a3);
        a4 = fmaf(__int_as_float(cv4.y), base[(unsigned)cv4.x * H_CH], a4);
        a5 = fmaf(__int_as_float(cv5.y), base[(unsigned)cv5.x * H_CH], a5);
        a6 = fmaf(__int_as_float(cv6.y), base[(unsigned)cv6.x * H_CH], a6);
        a7 = fmaf(__int_as_float(cv7.y), base[(unsigned)cv7.x * H_CH], a7);
    }
    for (; e + 4 <= e1; e += 4) {
        int2 cv0 = csr[e], cv1 = csr[e + 1], cv2 = csr[e + 2], cv3 = csr[e + 3];
        a0 = fmaf(__int_as_float(cv0.y), base[(unsigned)cv0.x * H_CH], a0);
        a1 = fmaf(__int_as_float(cv1.y), base[(unsigned)cv1.x * H_CH], a1);
        a2 = fmaf(__int_as_float(cv2.y), base[(unsigned)cv2.x * H_CH], a2);
        a3 = fmaf(__int_as_float(cv3.y), base[(unsigned)cv3.x * H_CH], a3);
    }
    for (; e < e1; ++e) {
        int2 cv = csr[e];
        a0 = fmaf(__int_as_float(cv.y), base[(unsigned)cv.x * H_CH], a0);
    }
    float s = ((a0 + a1) + (a2 + a3)) + ((a4 + a5) + (a6 + a7));
    size_t idxg = (size_t)r * GRP + lane;
    size_t idxf = (size_t)r * H_CH + goff + lane;
    float xr = x[idxf];
    float w0 = w[0], w1 = w[1], al = alpha_p[0];
    float t1 = s - xr;
    float o = -(w0 * xr + w1 * t1) + al * (xr - 0.5f * s);
    T1g[idxg] = t1;
    out[idxf] = o;
}

// ---------- chunked Chebyshev step (per 64-ch group) ----------
// All CBLK blocks co-resident; every wave owns RPWV consecutive rows and sweeps
// column chunks in the OUTER loop -> grid-wide soft-synchronized 8.4 MB gather
// window. Paired out-update: only odd k does the out RMW, applying
// w[k-1]*T_{k-1} + w[k]*T_k (tc is already loaded for the recurrence).
// Tnext may alias TprevBase (read-before-write per thread, no __restrict__).
__global__ __launch_bounds__(512, 8) void chebG_k(
    const int* __restrict__ rcb, const int2* __restrict__ csr,
    const float* __restrict__ Tcur, const float* TprevBase, int tprevStride,
    float* Tnext, float* __restrict__ out,
    const float* __restrict__ w, int k, int goff) {
    int wv = blockIdx.x * 8 + (threadIdx.x >> 6);
    int r0 = __builtin_amdgcn_readfirstlane(wv) * RPWV;
    int lane = threadIdx.x & 63;
    const float* base = Tcur + lane;          // gather Tcur[col*64 + lane]

    float acc[RPWV];
#pragma unroll
    for (int j = 0; j < RPWV; ++j) acc[j] = 0.f;

    for (int c = 0; c < NCH; ++c) {
#pragma unroll
        for (int j = 0; j < RPWV; ++j) {
            const int* rb = rcb + (size_t)(r0 + j) * 8 + c;
            int e0 = rb[0], e1 = rb[1];
            float a = acc[j];
            for (int e = e0; e < e1; ++e) {
                int2 cv = csr[e];
                a = fmaf(__int_as_float(cv.y), base[(unsigned)cv.x * GRP], a);
            }
            acc[j] = a;
        }
    }

    float wk = w[k], wkm1 = w[k - 1];
    bool doOut = (k & 1) != 0;
#pragma unroll
    for (int j = 0; j < RPWV; ++j) {
        int r = r0 + j;
        size_t idxg = (size_t)r * GRP + lane;
        float tc = Tcur[idxg];
        float tp = TprevBase[(size_t)r * tprevStride + lane];
        float tn = 2.0f * (acc[j] - tc) - tp;
        Tnext[idxg] = tn;
        if (doOut) {
            size_t idxf = (size_t)r * H_CH + goff + lane;
            out[idxf] -= wkm1 * tc + wk * tn;
        }
    }
}

extern "C" void kernel_launch(void* const* d_in, const int* in_sizes, int n_in,
                              void* d_out, int out_size, void* d_ws, size_t ws_size,
                              hipStream_t stream) {
    const float* x      = (const float*)d_in[0];
    const float* vals   = (const float*)d_in[1];
    const float* logits = (const float*)d_in[2];
    const float* alpha  = (const float*)d_in[3];
    const int*   erow   = (const int*)d_in[4];
    const int*   ecol   = (const int*)d_in[5];
    float* out = (float*)d_out;

    const size_t NG = (size_t)N_NODES * GRP;       // per-group T elements
    float* bufA    = (float*)d_ws;                 // N x 64
    float* bufB    = bufA + NG;                    // N x 64
    int2*  csr     = (int2*)(bufB + NG);           // packed col+val, chunk-grouped
    uint2* stag    = (uint2*)bufA;                 // aliases bufA: dead after build,
                                                   // bufA first written at k=2
    int*   row_ptr = (int*)(csr + NNZ_E);          // N+1 (first_k)
    int*   rcb     = row_ptr + (N_NODES + 1);      // N x 8 chunk boundaries
    int*   gfill   = rcb + (size_t)N_NODES * 8;    // NBUCK
    int*   bbase   = gfill + NBUCK;                // NBUCK
    float* w_buf   = (float*)(bbase + NBUCK);      // 16

    hipMemsetAsync(gfill, 0, NBUCK * sizeof(int), stream);
    softmax_k<<<1, 64, 0, stream>>>(logits, w_buf);

    int nblkA = (NNZ_E + EPB - 1) / EPB;
    bucketA_k<<<nblkA, 256, 0, stream>>>(erow, ecol, vals, gfill, stag, NNZ_E);
    scanG_k<<<1, 256, 0, stream>>>(gfill, bbase, row_ptr);
    bucketB_k<<<NBUCK, 256, 0, stream>>>(stag, gfill, bbase, row_ptr, rcb, csr);
    // build done: stag (alias of bufA) dead before bufA's first write (k=2)

    int gridF = (N_NODES + 7) / 8;                 // 25000 blocks, 8 waves each

    for (int g = 0; g < H_CH / GRP; ++g) {
        int goff = g * GRP;
        // T1 (compact) -> bufB; out slice initialized with w0,w1,alpha terms
        first_k<<<gridF, 512, 0, stream>>>(row_ptr, csr, x, bufB, out, w_buf, alpha, goff);
        // k = 2: Tprev = x slice (stride 128), Tnext -> bufA, no out RMW (even)
        chebG_k<<<CBLK, 512, 0, stream>>>(rcb, csr, bufB, x + goff, H_CH, bufA,
                                          out, w_buf, 2, goff);
        // k = 3..15: ping-pong; Tnext aliases Tprev; out RMW on odd k only
        float* Tcur = bufA;
        float* Tprev = bufB;
        for (int k = 3; k <= K_DEG; ++k) {
            chebG_k<<<CBLK, 512, 0, stream>>>(rcb, csr, Tcur, Tprev, GRP, Tprev,
                                              out, w_buf, k, goff);
            float* t = Tcur; Tcur = Tprev; Tprev = t;
        }
    }
}

// Round 7
// 4371.879 us; speedup vs baseline: 1.6632x; 1.6632x over previous
//
#include <hip/hip_runtime.h>
#include <math.h>

#define N_NODES 200000
#define H_CH    128
#define NNZ_E   3200000
#define K_DEG   15

// bucketed CSR build parameters
#define EPB     4096        // edges per block in bucket pass A
#define BSHIFT  9           // 512 rows per bucket
#define BROWS   512
#define NBUCK   391         // ceil(200000 / 512)
#define BCAP    9216        // per-bucket staging capacity (mean 8192, +11 sigma)

// ---------- softmax over 16 logits ----------
__global__ void softmax_k(const float* __restrict__ logits, float* __restrict__ w) {
    if (threadIdx.x == 0) {
        float m = -1e30f;
        for (int i = 0; i <= K_DEG; ++i) m = fmaxf(m, logits[i]);
        float e[K_DEG + 1];
        float s = 0.f;
        for (int i = 0; i <= K_DEG; ++i) { e[i] = expf(logits[i] - m); s += e[i]; }
        float inv = 1.0f / s;
        for (int i = 0; i <= K_DEG; ++i) w[i] = e[i] * inv;
    }
}

// ---------- bucket pass A: block-local LDS binning by row bucket ----------
__global__ __launch_bounds__(256) void bucketA_k(
    const int* __restrict__ row, const int* __restrict__ col,
    const float* __restrict__ vals,
    int* __restrict__ gfill, uint2* __restrict__ stag, int nnz) {
    __shared__ int cnt[NBUCK];
    __shared__ int excl[NBUCK];
    __shared__ int gbase[NBUCK];
    __shared__ int sm[256];
    __shared__ uint2 sstag[EPB];
    __shared__ unsigned short sb[EPB];

    int tid = threadIdx.x;
    int base = blockIdx.x * EPB;

    for (int t = tid; t < NBUCK; t += 256) cnt[t] = 0;
    __syncthreads();

    int r[16], c[16], b[16];
    float v[16];
#pragma unroll
    for (int j = 0; j < 16; ++j) {
        int i = base + j * 256 + tid;
        if (i < nnz) {
            r[j] = row[i]; c[j] = col[i]; v[j] = vals[i];
            b[j] = r[j] >> BSHIFT;
            atomicAdd(&cnt[b[j]], 1);
        } else {
            b[j] = -1;
        }
    }
    __syncthreads();

    {
        int b0 = 2 * tid, b1 = 2 * tid + 1;
        int c0 = (b0 < NBUCK) ? cnt[b0] : 0;
        int c1 = (b1 < NBUCK) ? cnt[b1] : 0;
        int pair = c0 + c1;
        sm[tid] = pair;
        __syncthreads();
        int incl = pair;
        for (int off = 1; off < 256; off <<= 1) {
            int tv = (tid >= off) ? sm[tid - off] : 0;
            __syncthreads();
            incl += tv;
            sm[tid] = incl;
            __syncthreads();
        }
        int pexcl = incl - pair;
        if (b0 < NBUCK) excl[b0] = pexcl;
        if (b1 < NBUCK) excl[b1] = pexcl + c0;
    }
    __syncthreads();

    for (int t = tid; t < NBUCK; t += 256) {
        int cb = cnt[t];
        gbase[t] = (cb > 0) ? atomicAdd(&gfill[t], cb) : 0;
    }
    __syncthreads();
    for (int t = tid; t < NBUCK; t += 256) cnt[t] = excl[t];
    __syncthreads();

#pragma unroll
    for (int j = 0; j < 16; ++j) {
        if (b[j] >= 0) {
            int p = atomicAdd(&cnt[b[j]], 1);
            sstag[p] = make_uint2(((unsigned)(r[j] & 511) << 18) | (unsigned)c[j],
                                  __float_as_uint(v[j]));
            sb[p] = (unsigned short)b[j];
        }
    }
    __syncthreads();

    int tot = nnz - base; if (tot > EPB) tot = EPB;
    for (int i = tid; i < tot; i += 256) {
        int bb = sb[i];
        size_t gp = (size_t)bb * BCAP + gbase[bb] + (i - excl[bb]);
        stag[gp] = sstag[i];
    }
}

// ---------- tiny scan over 391 bucket totals ----------
__global__ void scanG_k(const int* __restrict__ gfill, int* __restrict__ bbase,
                        int* __restrict__ row_ptr) {
    __shared__ int sm[256];
    int tid = threadIdx.x;
    int j0 = 2 * tid, j1 = 2 * tid + 1;
    int c0 = (j0 < NBUCK) ? gfill[j0] : 0;
    int c1 = (j1 < NBUCK) ? gfill[j1] : 0;
    int pair = c0 + c1;
    sm[tid] = pair;
    __syncthreads();
    int incl = pair;
    for (int off = 1; off < 256; off <<= 1) {
        int t = (tid >= off) ? sm[tid - off] : 0;
        __syncthreads();
        incl += t;
        sm[tid] = incl;
        __syncthreads();
    }
    int pexcl = incl - pair;
    if (j0 < NBUCK) bbase[j0] = pexcl;
    if (j1 < NBUCK) bbase[j1] = pexcl + c0;
    if (tid == 0) row_ptr[N_NODES] = NNZ_E;
}

// ---------- bucket pass B: bucket-local CSR build (R4-verified form) ----------
__global__ __launch_bounds__(256) void bucketB_k(
    const uint2* __restrict__ stag, const int* __restrict__ gfill,
    const int* __restrict__ bbase, int* __restrict__ row_ptr,
    int2* __restrict__ csr) {
    __shared__ int hist[BROWS];
    __shared__ int lexcl[BROWS];
    __shared__ int sm[256];
    int b = blockIdx.x;
    int n = gfill[b];
    int cs = bbase[b];
    const uint2* s = stag + (size_t)b * BCAP;
    int tid = threadIdx.x;

    hist[tid] = 0; hist[tid + 256] = 0;
    __syncthreads();
    for (int i = tid; i < n; i += 256)
        atomicAdd(&hist[s[i].x >> 18], 1);
    __syncthreads();

    int j0 = 2 * tid, j1 = 2 * tid + 1;
    int c0 = hist[j0], c1 = hist[j1];
    int pair = c0 + c1;
    sm[tid] = pair;
    __syncthreads();
    int incl = pair;
    for (int off = 1; off < 256; off <<= 1) {
        int t = (tid >= off) ? sm[tid - off] : 0;
        __syncthreads();
        incl += t;
        sm[tid] = incl;
        __syncthreads();
    }
    int pexcl = incl - pair;
    lexcl[j0] = pexcl;
    lexcl[j1] = pexcl + c0;

    int rbase = b << BSHIFT;
    if (rbase + j0 < N_NODES) row_ptr[rbase + j0] = cs + lexcl[j0];
    if (rbase + j1 < N_NODES) row_ptr[rbase + j1] = cs + lexcl[j1];
    hist[j0] = lexcl[j0];
    hist[j1] = lexcl[j1];
    __syncthreads();

    for (int i = tid; i < n; i += 256) {
        uint2 e = s[i];
        int rl = (int)(e.x >> 18);
        int p = cs + atomicAdd(&hist[rl], 1);
        int2 cv;
        cv.x = (int)(e.x & 0x3FFFF);
        cv.y = (int)e.y;
        csr[p] = cv;
    }
}

// ---------- first fused kernel, BOTH channel groups per wave ----------
// T layout [r][128]. Lane handles ch=lane and ch=lane+64: each csr edge is
// loaded ONCE for both groups (R4 read it twice), gather = 512B contiguous.
// S = spmm(x); T1 = S - x; out = -(w0*x + w1*T1) + alpha*(x - 0.5*S)
__global__ __launch_bounds__(512) void first2_k(
    const int* __restrict__ rp, const int2* __restrict__ csr,
    const float* __restrict__ x, float* __restrict__ T1, float* __restrict__ out,
    const float* __restrict__ w, const float* __restrict__ alpha_p) {
    int wid = blockIdx.x * 8 + (threadIdx.x >> 6);
    int r = __builtin_amdgcn_readfirstlane(wid);
    if (r >= N_NODES) return;
    int lane = threadIdx.x & 63;
    const float* g0 = x + lane;           // group 0: x[c*128 + lane]
    const float* g1 = x + 64 + lane;      // group 1: x[c*128 + 64 + lane]
    int e0 = rp[r], e1 = rp[r + 1];
    float a0 = 0.f, a1 = 0.f, a2 = 0.f, a3 = 0.f;
    float b0 = 0.f, b1 = 0.f, b2 = 0.f, b3 = 0.f;
    int e = e0;
    for (; e + 4 <= e1; e += 4) {
        int2 cv0 = csr[e], cv1 = csr[e + 1], cv2 = csr[e + 2], cv3 = csr[e + 3];
        unsigned o0 = (unsigned)cv0.x * H_CH, o1 = (unsigned)cv1.x * H_CH;
        unsigned o2 = (unsigned)cv2.x * H_CH, o3 = (unsigned)cv3.x * H_CH;
        float v0 = __int_as_float(cv0.y), v1 = __int_as_float(cv1.y);
        float v2 = __int_as_float(cv2.y), v3 = __int_as_float(cv3.y);
        a0 = fmaf(v0, g0[o0], a0);  b0 = fmaf(v0, g1[o0], b0);
        a1 = fmaf(v1, g0[o1], a1);  b1 = fmaf(v1, g1[o1], b1);
        a2 = fmaf(v2, g0[o2], a2);  b2 = fmaf(v2, g1[o2], b2);
        a3 = fmaf(v3, g0[o3], a3);  b3 = fmaf(v3, g1[o3], b3);
    }
    for (; e < e1; ++e) {
        int2 cv = csr[e];
        unsigned o = (unsigned)cv.x * H_CH;
        float v = __int_as_float(cv.y);
        a0 = fmaf(v, g0[o], a0);  b0 = fmaf(v, g1[o], b0);
    }
    float s0 = (a0 + a1) + (a2 + a3);
    float s1 = (b0 + b1) + (b2 + b3);
    size_t idx0 = (size_t)r * H_CH + lane;
    size_t idx1 = idx0 + 64;
    float xr0 = x[idx0], xr1 = x[idx1];
    float w0 = w[0], w1 = w[1], al = alpha_p[0];
    float t10 = s0 - xr0, t11 = s1 - xr1;
    T1[idx0] = t10;
    T1[idx1] = t11;
    out[idx0] = -(w0 * xr0 + w1 * t10) + al * (xr0 - 0.5f * s0);
    out[idx1] = -(w0 * xr1 + w1 * t11) + al * (xr1 - 0.5f * s1);
}

// ---------- Chebyshev step, BOTH groups per wave + paired out-update ----------
// Tn = 2*(spmm(Tc) - Tc) - Tp.  Out RMW only on odd k, applying
// w[k-1]*T_{k-1} + w[k]*T_k (tc is loaded anyway for the recurrence):
// halves out streaming traffic. Tnext may alias Tprev (each thread reads
// its tp before writing tn to the same address; no __restrict__ on either).
__global__ __launch_bounds__(512) void cheb2_k(
    const int* __restrict__ rp, const int2* __restrict__ csr,
    const float* __restrict__ Tcur, const float* Tprev,
    float* Tnext, float* __restrict__ out,
    const float* __restrict__ w, int k) {
    int wid = blockIdx.x * 8 + (threadIdx.x >> 6);
    int r = __builtin_amdgcn_readfirstlane(wid);
    if (r >= N_NODES) return;
    int lane = threadIdx.x & 63;
    const float* g0 = Tcur + lane;
    const float* g1 = Tcur + 64 + lane;
    int e0 = rp[r], e1 = rp[r + 1];
    float a0 = 0.f, a1 = 0.f, a2 = 0.f, a3 = 0.f;
    float b0 = 0.f, b1 = 0.f, b2 = 0.f, b3 = 0.f;
    int e = e0;
    for (; e + 4 <= e1; e += 4) {
        int2 cv0 = csr[e], cv1 = csr[e + 1], cv2 = csr[e + 2], cv3 = csr[e + 3];
        unsigned o0 = (unsigned)cv0.x * H_CH, o1 = (unsigned)cv1.x * H_CH;
        unsigned o2 = (unsigned)cv2.x * H_CH, o3 = (unsigned)cv3.x * H_CH;
        float v0 = __int_as_float(cv0.y), v1 = __int_as_float(cv1.y);
        float v2 = __int_as_float(cv2.y), v3 = __int_as_float(cv3.y);
        a0 = fmaf(v0, g0[o0], a0);  b0 = fmaf(v0, g1[o0], b0);
        a1 = fmaf(v1, g0[o1], a1);  b1 = fmaf(v1, g1[o1], b1);
        a2 = fmaf(v2, g0[o2], a2);  b2 = fmaf(v2, g1[o2], b2);
        a3 = fmaf(v3, g0[o3], a3);  b3 = fmaf(v3, g1[o3], b3);
    }
    for (; e < e1; ++e) {
        int2 cv = csr[e];
        unsigned o = (unsigned)cv.x * H_CH;
        float v = __int_as_float(cv.y);
        a0 = fmaf(v, g0[o], a0);  b0 = fmaf(v, g1[o], b0);
    }
    float s0 = (a0 + a1) + (a2 + a3);
    float s1 = (b0 + b1) + (b2 + b3);
    size_t idx0 = (size_t)r * H_CH + lane;
    size_t idx1 = idx0 + 64;
    float tc0 = Tcur[idx0], tc1 = Tcur[idx1];
    float tp0 = Tprev[idx0], tp1 = Tprev[idx1];   // read before Tnext writes (alias)
    float tn0 = 2.0f * (s0 - tc0) - tp0;
    float tn1 = 2.0f * (s1 - tc1) - tp1;
    Tnext[idx0] = tn0;
    Tnext[idx1] = tn1;
    if (k & 1) {
        float wk = w[k], wkm1 = w[k - 1];
        out[idx0] -= wkm1 * tc0 + wk * tn0;
        out[idx1] -= wkm1 * tc1 + wk * tn1;
    }
}

extern "C" void kernel_launch(void* const* d_in, const int* in_sizes, int n_in,
                              void* d_out, int out_size, void* d_ws, size_t ws_size,
                              hipStream_t stream) {
    const float* x      = (const float*)d_in[0];
    const float* vals   = (const float*)d_in[1];
    const float* logits = (const float*)d_in[2];
    const float* alpha  = (const float*)d_in[3];
    const int*   erow   = (const int*)d_in[4];
    const int*   ecol   = (const int*)d_in[5];
    float* out = (float*)d_out;

    const size_t NF = (size_t)N_NODES * H_CH;      // full-width T elements
    float* bufA    = (float*)d_ws;                 // N x 128
    float* bufB    = bufA + NF;                    // N x 128
    int2*  csr     = (int2*)(bufB + NF);           // packed col+val
    uint2* stag    = (uint2*)bufA;                 // aliases bufA (28.8 MB <= 102.4):
                                                   // dead after build; bufA first
                                                   // written at k=2
    int*   row_ptr = (int*)(csr + NNZ_E);          // N+1
    int*   gfill   = row_ptr + (N_NODES + 1);      // NBUCK
    int*   bbase   = gfill + NBUCK;                // NBUCK
    float* w_buf   = (float*)(bbase + NBUCK);      // 16

    hipMemsetAsync(gfill, 0, NBUCK * sizeof(int), stream);
    softmax_k<<<1, 64, 0, stream>>>(logits, w_buf);

    int nblkA = (NNZ_E + EPB - 1) / EPB;
    bucketA_k<<<nblkA, 256, 0, stream>>>(erow, ecol, vals, gfill, stag, NNZ_E);
    scanG_k<<<1, 256, 0, stream>>>(gfill, bbase, row_ptr);
    bucketB_k<<<NBUCK, 256, 0, stream>>>(stag, gfill, bbase, row_ptr, csr);
    // build done: stag (alias of bufA) dead before bufA's first write (k=2)

    int grid = (N_NODES + 7) / 8;                  // 8 waves (rows) per 512-thread block

    // T1 -> bufB (full width); out initialized with w0,w1,alpha terms
    first2_k<<<grid, 512, 0, stream>>>(row_ptr, csr, x, bufB, out, w_buf, alpha);
    // k = 2: Tprev = x (same [r][128] layout); Tnext -> bufA; no out RMW (even k)
    cheb2_k<<<grid, 512, 0, stream>>>(row_ptr, csr, bufB, x, bufA, out, w_buf, 2);
    // k = 3..15: ping-pong; Tnext aliases Tprev; out RMW on odd k applies both
    float* Tcur = bufA;
    float* Tprev = bufB;
    for (int k = 3; k <= K_DEG; ++k) {
        cheb2_k<<<grid, 512, 0, stream>>>(row_ptr, csr, Tcur, Tprev, Tprev,
                                          out, w_buf, k);
        float* t = Tcur; Tcur = Tprev; Tprev = t;
    }
}